// Round 1
// baseline (607.239 us; speedup 1.0000x reference)
//
#include <hip/hip_runtime.h>

// Fused attention fwd: R = softmax(Q K^T / sqrt(D)) V, plus attn weights P.
// B=16, LQ=LK=2048, D=128, fp32 in/out.
//
// Round 4: swapped-operand QK^T (compute S^T = K*Q^T, so C-frag has q=lane,
// keys in regs). Consequences:
//  - softmax is per-lane scalar (rinv = 1 float/lane, no shuffle reduces)
//  - K A-frags load DIRECTLY from global (2xf32x4 per kk) -- no K LDS at all;
//    wm-pair duplication is L1-absorbed (same CU, same time)
//  - pass 1 is LDS-free and barrier-free (32 barriers -> 1)
//  - pass 2: 2 barriers/iter (was 3); LDS only Vt (XOR-swizzled, unchanged)
//    + Ps (b64 writes from regs; same read patterns for P-store + PV A-frags)
//  - LDS 45.5KB -> 27.5KB; freed VGPRs fund full-iter K(64)+V(32) prefetch
//    (grid=512 caps us at 2 blocks/CU regardless, so VGPR<=256 is free).

#define NB  16
#define SLQ 2048
#define SLK 2048
#define DH  128
#define BQ  64
#define BK  64

typedef __bf16 bf16;
typedef bf16  bf16x8 __attribute__((ext_vector_type(8)));
typedef bf16  bf16x4 __attribute__((ext_vector_type(4)));
typedef bf16  bf16x2 __attribute__((ext_vector_type(2)));
typedef float f32x4  __attribute__((ext_vector_type(4)));
typedef float f32x16 __attribute__((ext_vector_type(16)));

#define SCALE 0.088388347648318447f  // 1/sqrt(128)

__device__ __forceinline__ f32x16 mfma32(bf16x8 a, bf16x8 b, f32x16 c) {
    return __builtin_amdgcn_mfma_f32_32x32x16_bf16(a, b, c, 0, 0, 0);
}

__device__ __forceinline__ bf16x8 cvt8(f32x4 v0, f32x4 v1) {
    bf16x8 r;
    r[0] = (bf16)v0[0]; r[1] = (bf16)v0[1]; r[2] = (bf16)v0[2]; r[3] = (bf16)v0[3];
    r[4] = (bf16)v1[0]; r[5] = (bf16)v1[1]; r[6] = (bf16)v1[2]; r[7] = (bf16)v1[3];
    return r;
}

__device__ __forceinline__ bf16x8 cvt8s(f32x4 v0, f32x4 v1, float s) {
    bf16x8 r;
    r[0] = (bf16)(v0[0] * s); r[1] = (bf16)(v0[1] * s);
    r[2] = (bf16)(v0[2] * s); r[3] = (bf16)(v0[3] * s);
    r[4] = (bf16)(v1[0] * s); r[5] = (bf16)(v1[1] * s);
    r[6] = (bf16)(v1[2] * s); r[7] = (bf16)(v1[3] * s);
    return r;
}

__global__ __launch_bounds__(256, 2)
void attn_fused(const float* __restrict__ Q, const float* __restrict__ K,
                const float* __restrict__ V, float* __restrict__ Rout,
                float* __restrict__ Pout) {
    const int b = blockIdx.x, qt = blockIdx.y;   // batch-major: XCD = b % 8
    const int tid  = threadIdx.x;
    const int wave = tid >> 6, lane = tid & 63;
    const int n31 = lane & 31, h = lane >> 5;
    const int wm = wave & 1, wn = wave >> 1;     // wm: q-group, wn: key-half / d-half

    __shared__ __align__(16) bf16 Vt[128][72];   // [d][k] 16B-block XOR swizzle
    __shared__ __align__(16) bf16 Ps[64][72];    // [q][k] (stride 144B, b128-aligned)
    __shared__ float rsum[2][64];                // [wn][q]

    const float* Qb = Q + ((size_t)b * SLQ + qt * BQ) * DH;
    const float* Kb = K + (size_t)b * SLK * DH;
    const float* Vb = V + (size_t)b * SLK * DH;
    float* Rb = Rout + ((size_t)b * SLQ + qt * BQ) * DH;
    float* Pb = Pout + ((size_t)b * SLQ + qt * BQ) * SLK;

    // Q B-frags (q rows wm*32+n31, scale folded): B[k=kk*16+8h+j][q=n31]
    bf16x8 aq[8];
    {
        const float* qp = Qb + (size_t)(wm * 32 + n31) * DH + h * 8;
#pragma unroll
        for (int kk = 0; kk < 8; ++kk) {
            f32x4 v0 = *(const f32x4*)(qp + kk * 16);
            f32x4 v1 = *(const f32x4*)(qp + kk * 16 + 4);
            aq[kk] = cvt8s(v0, v1, SCALE);
        }
    }

    // per-lane K pointer: A-frag lane (n31,h) holds K[key0+n31][kk*16+8h+0..7]
    const float* kp0 = Kb + (size_t)(wn * 32 + n31) * DH + h * 8;

    // ---------------- pass 1: row sums (no LDS, no barriers) ----------------
    f32x4 kraw[16];
#pragma unroll
    for (int kk = 0; kk < 8; ++kk) {
        kraw[2 * kk]     = *(const f32x4*)(kp0 + kk * 16);
        kraw[2 * kk + 1] = *(const f32x4*)(kp0 + kk * 16 + 4);
    }

    float psum = 0.f;
    for (int kt = 0; kt < 32; ++kt) {
        bf16x8 kf[8];
#pragma unroll
        for (int kk = 0; kk < 8; ++kk) kf[kk] = cvt8(kraw[2 * kk], kraw[2 * kk + 1]);
        if (kt + 1 < 32) {
            const float* kp = kp0 + (kt + 1) * (64 * DH);
#pragma unroll
            for (int kk = 0; kk < 8; ++kk) {
                kraw[2 * kk]     = *(const f32x4*)(kp + kk * 16);
                kraw[2 * kk + 1] = *(const f32x4*)(kp + kk * 16 + 4);
            }
        }
        f32x16 c = (f32x16)0.0f;
#pragma unroll
        for (int kk = 0; kk < 8; ++kk) c = mfma32(kf[kk], aq[kk], c);
#pragma unroll
        for (int r = 0; r < 16; ++r) psum += __expf(c[r]);
    }

    // prefetch pass-2 tile 0 (K re-read is L2-hot)
    const int c5 = tid & 31;
    const int rp = ((tid >> 5) & 7) * 2;
    f32x4 vraw[8];
#pragma unroll
    for (int kk = 0; kk < 8; ++kk) {
        kraw[2 * kk]     = *(const f32x4*)(kp0 + kk * 16);
        kraw[2 * kk + 1] = *(const f32x4*)(kp0 + kk * 16 + 4);
    }
#pragma unroll
    for (int i = 0; i < 4; ++i) {
        const float* vp = Vb + (size_t)(rp + 16 * i) * DH + c5 * 4;
        vraw[2 * i]     = *(const f32x4*)vp;
        vraw[2 * i + 1] = *(const f32x4*)(vp + DH);
    }

    // merge h halves, then the two wn key-halves via LDS (single barrier)
    psum += __shfl_xor(psum, 32);
    if (lane < 32) rsum[wn][wm * 32 + n31] = psum;
    __syncthreads();
    const float rinv = 1.0f / (rsum[0][wm * 32 + n31] + rsum[1][wm * 32 + n31]);

    f32x16 racc[2];
    racc[0] = (f32x16)0.0f;
    racc[1] = (f32x16)0.0f;

    // ---------------- pass 2: P store + PV (BK=64, 32 tiles) ----------------
    const int qrow = wm * 32 + n31;
    for (int kt = 0; kt < 32; ++kt) {
        __syncthreads();   // A: prev-iter PV/P-store reads done; Vt/Ps writable
        // stage V transposed [d][k], 16B-block XOR swizzle pb = kb ^ ((d>>3)&7)
#pragma unroll
        for (int i = 0; i < 4; ++i) {
            int k0 = rp + 16 * i, kb = k0 >> 3, off = k0 & 7;
#pragma unroll
            for (int j = 0; j < 4; ++j) {
                int d = c5 * 4 + j;
                int pb = kb ^ ((d >> 3) & 7);
                bf16x2 pr;
                pr[0] = (bf16)vraw[2 * i][j];
                pr[1] = (bf16)vraw[2 * i + 1][j];
                *(bf16x2*)&Vt[d][pb * 8 + off] = pr;
            }
        }
        // K A-frags for this tile (from prefetched regs)
        bf16x8 kf[8];
#pragma unroll
        for (int kk = 0; kk < 8; ++kk) kf[kk] = cvt8(kraw[2 * kk], kraw[2 * kk + 1]);
        // prefetch next tile (flies across the rest of the iteration)
        if (kt + 1 < 32) {
            const float* kp = kp0 + (kt + 1) * (64 * DH);
#pragma unroll
            for (int kk = 0; kk < 8; ++kk) {
                kraw[2 * kk]     = *(const f32x4*)(kp + kk * 16);
                kraw[2 * kk + 1] = *(const f32x4*)(kp + kk * 16 + 4);
            }
#pragma unroll
            for (int i = 0; i < 4; ++i) {
                const float* vp = Vb + (size_t)((kt + 1) * 64 + rp + 16 * i) * DH + c5 * 4;
                vraw[2 * i]     = *(const f32x4*)vp;
                vraw[2 * i + 1] = *(const f32x4*)(vp + DH);
            }
        }
        // QK^T swapped: c = S^T tile, col = q (lane), rows = keys (regs)
        f32x16 c = (f32x16)0.0f;
#pragma unroll
        for (int kk = 0; kk < 8; ++kk) c = mfma32(kf[kk], aq[kk], c);
        // softmax numerator -> Ps, 4x b64 writes (keys consecutive in regs)
        // reg r -> key wn*32 + (r&3) + 8*(r>>2) + 4h
#pragma unroll
        for (int g = 0; g < 4; ++g) {
            bf16x4 pw;
            pw[0] = (bf16)(__expf(c[4 * g + 0]) * rinv);
            pw[1] = (bf16)(__expf(c[4 * g + 1]) * rinv);
            pw[2] = (bf16)(__expf(c[4 * g + 2]) * rinv);
            pw[3] = (bf16)(__expf(c[4 * g + 3]) * rinv);
            *(bf16x4*)&Ps[qrow][wn * 32 + 4 * h + 8 * g] = pw;
        }
        __syncthreads();   // B: Vt + Ps visible to all waves

        // P global store: row tid>>2, 16 cols/thread, 64B/4-lane coalesced
        {
            int prow = tid >> 2, kc = (tid & 3) * 16;
            float* dst = Pb + (size_t)prow * SLK + kt * 64 + kc;
#pragma unroll
            for (int u = 0; u < 2; ++u) {
                bf16x8 pv = *(const bf16x8*)&Ps[prow][kc + u * 8];
                f32x4 o0, o1;
                o0[0] = (float)pv[0]; o0[1] = (float)pv[1];
                o0[2] = (float)pv[2]; o0[3] = (float)pv[3];
                o1[0] = (float)pv[4]; o1[1] = (float)pv[5];
                o1[2] = (float)pv[6]; o1[3] = (float)pv[7];
                __builtin_nontemporal_store(o0, (f32x4*)(dst + u * 8));
                __builtin_nontemporal_store(o1, (f32x4*)(dst + u * 8 + 4));
            }
        }

        // PV: R rows wm*32+.., d-cols wn*64 + t*32 + n31
        bf16x8 ap[4];
#pragma unroll
        for (int kk = 0; kk < 4; ++kk)
            ap[kk] = *(const bf16x8*)&Ps[qrow][kk * 16 + 8 * h];
#pragma unroll
        for (int kk = 0; kk < 4; ++kk) {
#pragma unroll
            for (int t = 0; t < 2; ++t) {
                int d = wn * 64 + t * 32 + n31;
                int pb = (2 * kk + h) ^ ((d >> 3) & 7);
                bf16x8 bv = *(const bf16x8*)&Vt[d][pb * 8];
                racc[t] = mfma32(ap[kk], bv, racc[t]);
            }
        }
    }

    // epilogue: R store (C layout: col = wn*64+t*32+n31, row per reg map)
#pragma unroll
    for (int t = 0; t < 2; ++t)
#pragma unroll
        for (int r = 0; r < 16; ++r) {
            int row = wm * 32 + (r & 3) + 8 * (r >> 2) + 4 * h;
            int d   = wn * 64 + t * 32 + n31;
            __builtin_nontemporal_store(racc[t][r], &Rb[(size_t)row * DH + d]);
        }
}

extern "C" void kernel_launch(void* const* d_in, const int* in_sizes, int n_in,
                              void* d_out, int out_size, void* d_ws, size_t ws_size,
                              hipStream_t stream) {
    (void)in_sizes; (void)n_in; (void)out_size; (void)d_ws; (void)ws_size;
    const float* Q = (const float*)d_in[0];
    const float* K = (const float*)d_in[1];
    const float* V = (const float*)d_in[2];
    float* R = (float*)d_out;
    float* P = (float*)d_out + (size_t)NB * SLQ * DH;

    dim3 grid(NB, SLQ / BQ);  // 512 blocks, batch-major for XCD L2 locality
    attn_fused<<<grid, 256, 0, stream>>>(Q, K, V, R, P);
}

// Round 2
// 433.329 us; speedup vs baseline: 1.4013x; 1.4013x over previous
//
#include <hip/hip_runtime.h>

// Fused attention fwd: R = softmax(Q K^T / sqrt(D)) V, plus attn weights P.
// B=16, LQ=LK=2048, D=128, fp32 in/out.
//
// Round 5. Post-mortem of r4 (382us vs r3 206us):
//  - r4 per-lane K frag loads from global were uncoalesced (16B/lane over 32
//    rows at 512B stride -> ~64 lines/instr) -> VMEM transaction-bound.
//    FIX: K back to coalesced LDS staging (r3 pattern).
//  - r4 P store covered each 64B line with 4 separate nontemporal instrs
//    (16B pieces at 64B lane stride) -> partial-line streaming writes ->
//    WRITE_SIZE 288->450MB. FIX: r3 quad pattern (each instr = full lines).
// Kept from r4 (numerically verified): swapped QK^T (S^T = K*Q^T) giving
// per-lane scalar softmax (rinv = 1 reg, no shuffle reduce) + b64 Ps writes.
// NEW: all __syncthreads() -> lgkmcnt(0)+s_barrier ("lgkm barrier", no
// vmcnt(0)). __syncthreads drains vmcnt0, so each iter waited for its 16KB
// of P stores to ack (effective write BW pinned at ~1.4TB/s). With
// lgkm-only barriers the stores stream across iterations; kreg/vreg
// prefetch consumption gets compiler-counted vmcnt (loads issue BEFORE the
// stores each iter, so the counted wait leaves stores in flight).

#define NB  16
#define SLQ 2048
#define SLK 2048
#define DH  128
#define BQ  64
#define BK  64

typedef __bf16 bf16;
typedef bf16  bf16x8 __attribute__((ext_vector_type(8)));
typedef bf16  bf16x4 __attribute__((ext_vector_type(4)));
typedef bf16  bf16x2 __attribute__((ext_vector_type(2)));
typedef float f32x4  __attribute__((ext_vector_type(4)));
typedef float f32x16 __attribute__((ext_vector_type(16)));

#define SCALE 0.088388347648318447f  // 1/sqrt(128)

__device__ __forceinline__ f32x16 mfma32(bf16x8 a, bf16x8 b, f32x16 c) {
    return __builtin_amdgcn_mfma_f32_32x32x16_bf16(a, b, c, 0, 0, 0);
}

__device__ __forceinline__ bf16x8 cvt8(f32x4 v0, f32x4 v1) {
    bf16x8 r;
    r[0] = (bf16)v0[0]; r[1] = (bf16)v0[1]; r[2] = (bf16)v0[2]; r[3] = (bf16)v0[3];
    r[4] = (bf16)v1[0]; r[5] = (bf16)v1[1]; r[6] = (bf16)v1[2]; r[7] = (bf16)v1[3];
    return r;
}

__device__ __forceinline__ bf16x8 cvt8s(f32x4 v0, f32x4 v1, float s) {
    bf16x8 r;
    r[0] = (bf16)(v0[0] * s); r[1] = (bf16)(v0[1] * s);
    r[2] = (bf16)(v0[2] * s); r[3] = (bf16)(v0[3] * s);
    r[4] = (bf16)(v1[0] * s); r[5] = (bf16)(v1[1] * s);
    r[6] = (bf16)(v1[2] * s); r[7] = (bf16)(v1[3] * s);
    return r;
}

// Workgroup barrier that waits only on LDS ops (lgkmcnt), NOT vmcnt.
// asm memory clobbers fence compiler reordering on both sides; hardware
// issues ds ops in order per-wave, so lgkmcnt(0) before s_barrier makes
// this wave's LDS writes visible to waves released by the barrier.
__device__ __forceinline__ void barrier_lgkm() {
    asm volatile("s_waitcnt lgkmcnt(0)" ::: "memory");
    __builtin_amdgcn_s_barrier();
    asm volatile("" ::: "memory");
}

__global__ __launch_bounds__(256, 2)
void attn_fused(const float* __restrict__ Q, const float* __restrict__ K,
                const float* __restrict__ V, float* __restrict__ Rout,
                float* __restrict__ Pout) {
    const int b = blockIdx.x, qt = blockIdx.y;   // batch-major: XCD = b % 8
    const int tid  = threadIdx.x;
    const int wave = tid >> 6, lane = tid & 63;
    const int n31 = lane & 31, h = lane >> 5;
    const int wm = wave & 1, wn = wave >> 1;     // wm: q-group, wn: key/d group

    // LDS: pass2 Ks[64][136] | Vt[128][72] | Ps[64][72] ; pass1 aliases
    // Ks1[128][136] (34816 B) over Ks+Vt. rsum[2][64] tail.
    __shared__ __align__(16) char smem[45056 + 512];
    bf16 (*Ks)[136]  = (bf16(*)[136])smem;
    bf16 (*Ks1)[136] = (bf16(*)[136])smem;
    bf16 (*Vt)[72]   = (bf16(*)[72])(smem + 17408);
    bf16 (*Ps)[72]   = (bf16(*)[72])(smem + 35840);
    float* rsum      = (float*)(smem + 45056);   // [wn][64]

    const float* Qb = Q + ((size_t)b * SLQ + qt * BQ) * DH;
    const float* Kb = K + (size_t)b * SLK * DH;
    const float* Vb = V + (size_t)b * SLK * DH;
    float* Rb = Rout + ((size_t)b * SLQ + qt * BQ) * DH;
    float* Pb = Pout + ((size_t)b * SLQ + qt * BQ) * SLK;

    // Q B-frags (q rows wm*32+n31, scale folded): B[k=kk*16+8h+j][q=n31]
    bf16x8 aq[8];
    {
        const float* qp = Qb + (size_t)(wm * 32 + n31) * DH + h * 8;
#pragma unroll
        for (int kk = 0; kk < 8; ++kk) {
            f32x4 v0 = *(const f32x4*)(qp + kk * 16);
            f32x4 v1 = *(const f32x4*)(qp + kk * 16 + 4);
            aq[kk] = cvt8s(v0, v1, SCALE);
        }
    }

    // ---------------- pass 1: row sums (BK=128, 16 tiles) ----------------
    // Swapped MFMA: c = S^T, col = q (lane), rows = keys (regs) ->
    // per-lane scalar accumulation, no cross-lane reduce until the end.
    float psum = 0.f;
    {
        f32x4 kreg[16];
#pragma unroll
        for (int i = 0; i < 8; ++i) {
            int f = tid + i * 256, row = f >> 4, g = f & 15;
            const float* kp = Kb + (size_t)row * DH + g * 8;
            kreg[2 * i]     = *(const f32x4*)kp;
            kreg[2 * i + 1] = *(const f32x4*)(kp + 4);
        }
        for (int kt = 0; kt < 16; ++kt) {
            barrier_lgkm();   // prior-iter frag reads done
#pragma unroll
            for (int i = 0; i < 8; ++i) {
                int f = tid + i * 256, row = f >> 4, g = f & 15;
                *(bf16x8*)&Ks1[row][g * 8] = cvt8(kreg[2 * i], kreg[2 * i + 1]);
            }
            barrier_lgkm();   // staging visible
            if (kt + 1 < 16) {
#pragma unroll
                for (int i = 0; i < 8; ++i) {
                    int f = tid + i * 256, row = f >> 4, g = f & 15;
                    const float* kp = Kb + (size_t)((kt + 1) * 128 + row) * DH + g * 8;
                    kreg[2 * i]     = *(const f32x4*)kp;
                    kreg[2 * i + 1] = *(const f32x4*)(kp + 4);
                }
            }
#pragma unroll
            for (int t = 0; t < 2; ++t) {
                f32x16 c = (f32x16)0.0f;
#pragma unroll
                for (int kk = 0; kk < 8; ++kk) {
                    bf16x8 kf = *(const bf16x8*)&Ks1[wn * 64 + t * 32 + n31][kk * 16 + h * 8];
                    c = mfma32(kf, aq[kk], c);
                }
#pragma unroll
                for (int r = 0; r < 16; ++r) psum += __expf(c[r]);
            }
        }
    }

    // prefetch pass-2 tile 0 (K re-read is L2-hot); overlaps the reduction
    const int c5 = tid & 31;
    const int rp = ((tid >> 5) & 7) * 2;
    f32x4 kreg2[8], vreg[8];
#pragma unroll
    for (int i = 0; i < 4; ++i) {
        int f = tid + i * 256, row = f >> 4, g = f & 15;
        const float* kp = Kb + (size_t)row * DH + g * 8;
        kreg2[2 * i]     = *(const f32x4*)kp;
        kreg2[2 * i + 1] = *(const f32x4*)(kp + 4);
        const float* vp = Vb + (size_t)(rp + i * 16) * DH + c5 * 4;
        vreg[2 * i]     = *(const f32x4*)vp;
        vreg[2 * i + 1] = *(const f32x4*)(vp + DH);
    }

    // merge h halves (shfl), then the two wn key-halves via LDS
    psum += __shfl_xor(psum, 32);
    if (lane < 32) rsum[wn * 64 + wm * 32 + n31] = psum;
    barrier_lgkm();
    const int qrow = wm * 32 + n31;
    const float rinv = 1.0f / (rsum[qrow] + rsum[64 + qrow]);

    f32x16 racc[2];
    racc[0] = (f32x16)0.0f;
    racc[1] = (f32x16)0.0f;

    // ---------------- pass 2: P store + PV (BK=64, 32 tiles) ----------------
    for (int kt = 0; kt < 32; ++kt) {
        barrier_lgkm();   // A: prev-iter PV/P-store LDS reads done
        // stage K tile [k][d] (coalesced regs -> LDS)
#pragma unroll
        for (int i = 0; i < 4; ++i) {
            int f = tid + i * 256, row = f >> 4, g = f & 15;
            *(bf16x8*)&Ks[row][g * 8] = cvt8(kreg2[2 * i], kreg2[2 * i + 1]);
        }
        // stage V transposed [d][k], 16B-block XOR swizzle pb = kb ^ ((d>>3)&7)
#pragma unroll
        for (int i = 0; i < 4; ++i) {
            int k0 = rp + i * 16;
            int kb = k0 >> 3, off = k0 & 7;
#pragma unroll
            for (int j = 0; j < 4; ++j) {
                int d = c5 * 4 + j;
                int pb = kb ^ ((d >> 3) & 7);
                bf16x2 pr;
                pr[0] = (bf16)vreg[2 * i][j];
                pr[1] = (bf16)vreg[2 * i + 1][j];
                *(bf16x2*)&Vt[d][pb * 8 + off] = pr;
            }
        }
        barrier_lgkm();   // B: Ks/Vt visible

        // QK^T swapped: c = S^T sub-tile (keys wn*32.., q-col = lane)
        f32x16 c = (f32x16)0.0f;
#pragma unroll
        for (int kk = 0; kk < 8; ++kk) {
            bf16x8 kf = *(const bf16x8*)&Ks[wn * 32 + n31][kk * 16 + h * 8];
            c = mfma32(kf, aq[kk], c);
        }
        // softmax -> Ps, 4x b64 writes (reg r -> key wn*32+(r&3)+8*(r>>2)+4h)
#pragma unroll
        for (int g = 0; g < 4; ++g) {
            bf16x4 pw;
            pw[0] = (bf16)(__expf(c[4 * g + 0]) * rinv);
            pw[1] = (bf16)(__expf(c[4 * g + 1]) * rinv);
            pw[2] = (bf16)(__expf(c[4 * g + 2]) * rinv);
            pw[3] = (bf16)(__expf(c[4 * g + 3]) * rinv);
            *(bf16x4*)&Ps[qrow][wn * 32 + 4 * h + 8 * g] = pw;
        }

        // prefetch next tile (issued BEFORE this iter's P stores, so the
        // next-iter staging wait is a counted vmcnt that skips the stores)
        if (kt + 1 < 32) {
#pragma unroll
            for (int i = 0; i < 4; ++i) {
                int f = tid + i * 256, row = f >> 4, g = f & 15;
                const float* kp = Kb + (size_t)((kt + 1) * 64 + row) * DH + g * 8;
                kreg2[2 * i]     = *(const f32x4*)kp;
                kreg2[2 * i + 1] = *(const f32x4*)(kp + 4);
                const float* vp = Vb + (size_t)((kt + 1) * 64 + rp + i * 16) * DH + c5 * 4;
                vreg[2 * i]     = *(const f32x4*)vp;
                vreg[2 * i + 1] = *(const f32x4*)(vp + DH);
            }
        }
        barrier_lgkm();   // C: Ps visible (cross-wave for P store + PV A-frags)

        // P global store: quad pattern, each instr covers full 64B lines
        {
            int prow = tid >> 2, pc = tid & 3;
            float* dst = Pb + (size_t)prow * SLK + kt * 64;
#pragma unroll
            for (int u = 0; u < 4; ++u) {
                bf16x4 pv = *(const bf16x4*)&Ps[prow][u * 16 + pc * 4];
                f32x4 o;
                o[0] = (float)pv[0]; o[1] = (float)pv[1];
                o[2] = (float)pv[2]; o[3] = (float)pv[3];
                __builtin_nontemporal_store(o, (f32x4*)(dst + u * 16 + pc * 4));
            }
        }

        // PV: R rows wm*32+.., d-cols wn*64 + t*32 + n31
#pragma unroll
        for (int kk = 0; kk < 4; ++kk) {
            bf16x8 ap = *(const bf16x8*)&Ps[qrow][kk * 16 + 8 * h];
#pragma unroll
            for (int t = 0; t < 2; ++t) {
                int d = wn * 64 + t * 32 + n31;
                int pb = (2 * kk + h) ^ ((d >> 3) & 7);
                bf16x8 bv = *(const bf16x8*)&Vt[d][pb * 8];
                racc[t] = mfma32(ap, bv, racc[t]);
            }
        }
    }

    // epilogue: R store (C layout: col = wn*64+t*32+n31, row per reg map)
#pragma unroll
    for (int t = 0; t < 2; ++t)
#pragma unroll
        for (int r = 0; r < 16; ++r) {
            int row = wm * 32 + (r & 3) + 8 * (r >> 2) + 4 * h;
            int d   = wn * 64 + t * 32 + n31;
            __builtin_nontemporal_store(racc[t][r], &Rb[(size_t)row * DH + d]);
        }
}

extern "C" void kernel_launch(void* const* d_in, const int* in_sizes, int n_in,
                              void* d_out, int out_size, void* d_ws, size_t ws_size,
                              hipStream_t stream) {
    (void)in_sizes; (void)n_in; (void)out_size; (void)d_ws; (void)ws_size;
    const float* Q = (const float*)d_in[0];
    const float* K = (const float*)d_in[1];
    const float* V = (const float*)d_in[2];
    float* R = (float*)d_out;
    float* P = (float*)d_out + (size_t)NB * SLQ * DH;

    dim3 grid(NB, SLQ / BQ);  // 512 blocks, batch-major for XCD L2 locality
    attn_fused<<<grid, 256, 0, stream>>>(Q, K, V, R, P);
}